// Round 6
// baseline (239.516 us; speedup 1.0000x reference)
//
#include <hip/hip_runtime.h>

// Holt-Winters, row-per-lane compute + double-buffered LDS out-tile with
// DELAYED drain. 128 blocks x 64 threads (1 wave each); block owns 64 rows.
//
// Stall model this round: global_store WAR register-reuse forces vmcnt waits
// on store COMPLETION (~500-900 cyc). Fix: window m's drain handles window
// m-1's tile (double-buffered LDS), with all 24 float4 drain temps live at
// once (loads / compiler barrier / stores) so no register is rewritten until
// the next drain, a full ~5800-cyc window later.
//
//  - state (L, c=L+b): 2 dependent FMAs/step; 8 VALU ops/step total
//  - x prefetched via 6 rotating 24-float register chunks (144-step lookahead)
//  - LDS [2][64][100] (51.2 KB); stride 100 dwords == contiguous bank pattern
//  - drain: 8 lanes x float4 = 32 contiguous floats per row (full 64B lines)
//  - every register-array index compile-time constant (rule #20)
// Hardcoded schedule for N multiple of 64, T = 2048.

#define STR2 100

__global__ __launch_bounds__(64, 1) void hw_kernel(
    const float* __restrict__ temp,
    const float* __restrict__ alpha,
    const float* __restrict__ beta,
    const float* __restrict__ gamma,
    const float* __restrict__ L0,
    const float* __restrict__ b0,
    const float* __restrict__ S0,
    float* __restrict__ out,
    int N, int T)
{
    __shared__ float ot[2 * 64 * STR2];      // 51.2 KB

    const int lane = threadIdx.x;            // 0..63, owns one row
    const int row0 = blockIdx.x * 64;
    const int row  = row0 + lane;

    const float a_  = alpha[0];
    const float bt  = beta[0];
    const float g_  = gamma[0];
    const float oma = 1.0f - a_;
    const float omb = 1.0f - bt;
    const float opb = 1.0f + bt;

    const float* xrow = temp + (size_t)row * T;

    float x0[24], x1[24], x2[24], x3[24], x4[24], x5[24], buf[24];
    float L, c;
    float og[4] = {0.f, 0.f, 0.f, 0.f};

#define LOADG(B, T0, J) \
    if ((T0) + 4*(J) + 4 <= T) { \
        const float4 v = *reinterpret_cast<const float4*>(xrow + (T0) + 4*(J)); \
        B[4*(J)+0]=v.x; B[4*(J)+1]=v.y; B[4*(J)+2]=v.z; B[4*(J)+3]=v.w; }
#define LOADX(B, T0) { LOADG(B,(T0),0) LOADG(B,(T0),1) LOADG(B,(T0),2) \
                       LOADG(B,(T0),3) LOADG(B,(T0),4) LOADG(B,(T0),5) }

    // Prime 6 chunks (t = 0..143) and the state.
    LOADX(x0, 0)   LOADX(x1, 24)  LOADX(x2, 48)
    LOADX(x3, 72)  LOADX(x4, 96)  LOADX(x5, 120)
    {
        const float* s0r = S0 + (size_t)row * 24;
        #pragma unroll
        for (int p = 0; p < 6; ++p) {
            const float4 v = *reinterpret_cast<const float4*>(s0r + 4*p);
            buf[4*p+0]=v.x; buf[4*p+1]=v.y; buf[4*p+2]=v.z; buf[4*p+3]=v.w;
        }
        L = L0[row];
        c = L + b0[row];
    }

    // One step at t = wbase + 24*Q + K; phase == K. P = LDS buffer parity.
    // 8 VALU ops; dependent chain c -> Ln -> cn (2 FMAs).
#define STEPQ(K, B, Q, P) { \
    const float x  = B[(K)]; \
    const float s  = buf[(K)]; \
    const float t  = x - s; \
    const float at = a_ * t; \
    const float Ln = fmaf(oma, c, at); \
    const float t1 = fmaf(omb, c, -L); \
    const float cn = fmaf(opb, Ln, t1); \
    const float sn = fmaf(g_, t - Ln, s); \
    buf[(K)] = sn; \
    og[(K)&3] = cn * sn; \
    L = Ln; c = cn; \
    if (((K)&3) == 3) \
        *reinterpret_cast<float4*>(&ot[(P)*64*STR2 + lane*STR2 + 24*(Q) + ((K)-3)]) = \
            make_float4(og[0], og[1], og[2], og[3]); }

#define CHUNK(B, Q, P) { \
    STEPQ(0,B,Q,P)  STEPQ(1,B,Q,P)  STEPQ(2,B,Q,P)  STEPQ(3,B,Q,P)  \
    STEPQ(4,B,Q,P)  STEPQ(5,B,Q,P)  STEPQ(6,B,Q,P)  STEPQ(7,B,Q,P)  \
    STEPQ(8,B,Q,P)  STEPQ(9,B,Q,P)  STEPQ(10,B,Q,P) STEPQ(11,B,Q,P) \
    STEPQ(12,B,Q,P) STEPQ(13,B,Q,P) STEPQ(14,B,Q,P) STEPQ(15,B,Q,P) \
    STEPQ(16,B,Q,P) STEPQ(17,B,Q,P) STEPQ(18,B,Q,P) STEPQ(19,B,Q,P) \
    STEPQ(20,B,Q,P) STEPQ(21,B,Q,P) STEPQ(22,B,Q,P) STEPQ(23,B,Q,P) }

#define TSTEPQ(K, B, Q, P, TF) if ((TF) + 24*(Q) + (K) < T) STEPQ(K, B, Q, P)
#define TCHUNK(B, Q, P, TF) { \
    TSTEPQ(0,B,Q,P,TF)  TSTEPQ(1,B,Q,P,TF)  TSTEPQ(2,B,Q,P,TF)  TSTEPQ(3,B,Q,P,TF)  \
    TSTEPQ(4,B,Q,P,TF)  TSTEPQ(5,B,Q,P,TF)  TSTEPQ(6,B,Q,P,TF)  TSTEPQ(7,B,Q,P,TF)  \
    TSTEPQ(8,B,Q,P,TF)  TSTEPQ(9,B,Q,P,TF)  TSTEPQ(10,B,Q,P,TF) TSTEPQ(11,B,Q,P,TF) \
    TSTEPQ(12,B,Q,P,TF) TSTEPQ(13,B,Q,P,TF) TSTEPQ(14,B,Q,P,TF) TSTEPQ(15,B,Q,P,TF) \
    TSTEPQ(16,B,Q,P,TF) TSTEPQ(17,B,Q,P,TF) TSTEPQ(18,B,Q,P,TF) TSTEPQ(19,B,Q,P,TF) \
    TSTEPQ(20,B,Q,P,TF) TSTEPQ(21,B,Q,P,TF) TSTEPQ(22,B,Q,P,TF) TSTEPQ(23,B,Q,P,TF) }

#define WINDOW(P0, P1, P2, P3, WT, PB) { \
    CHUNK(P0, 0, PB) LOADX(P0, (WT) + 144)      \
    CHUNK(P1, 1, PB) LOADX(P1, (WT) + 144 + 24) \
    CHUNK(P2, 2, PB) LOADX(P2, (WT) + 144 + 48) \
    CHUNK(P3, 3, PB) LOADX(P3, (WT) + 144 + 72) }

    // Drain one 96-col window from LDS buffer PB starting at out col W0.
    // ALL 24 float4 temps live across the barrier -> no WAR reuse until the
    // next drain. 8 lanes x 16B = 32 contiguous floats per row per instr.
    const int dr2 = lane >> 3;      // 0..7 row within group
    const int dc  = lane & 7;       // 0..7 float4 column
#define DRAIN(PB, W0) { \
    float4 dv[24]; \
    _Pragma("unroll") for (int rg = 0; rg < 8; ++rg) { \
      _Pragma("unroll") for (int j = 0; j < 3; ++j) { \
        dv[rg*3+j] = *reinterpret_cast<const float4*>( \
            &ot[(PB)*64*STR2 + (8*rg + dr2)*STR2 + 32*j + 4*dc]); \
    } } \
    asm volatile("" ::: "memory"); \
    _Pragma("unroll") for (int rg = 0; rg < 8; ++rg) { \
      _Pragma("unroll") for (int j = 0; j < 3; ++j) { \
        *reinterpret_cast<float4*>( \
            out + (size_t)(row0 + 8*rg + dr2)*T + (W0) + 32*j + 4*dc) = dv[rg*3+j]; \
    } } }

    // ---- Window 0 (head) -> ot[0]: t=0 special, then t = 1..95 ----
    og[0] = c * buf[0];              // out[:,0] = (L0+b0)*S0[:,0]
    STEPQ(1,x0,0,0)  STEPQ(2,x0,0,0)  STEPQ(3,x0,0,0)
    STEPQ(4,x0,0,0)  STEPQ(5,x0,0,0)  STEPQ(6,x0,0,0)  STEPQ(7,x0,0,0)
    STEPQ(8,x0,0,0)  STEPQ(9,x0,0,0)  STEPQ(10,x0,0,0) STEPQ(11,x0,0,0)
    STEPQ(12,x0,0,0) STEPQ(13,x0,0,0) STEPQ(14,x0,0,0) STEPQ(15,x0,0,0)
    STEPQ(16,x0,0,0) STEPQ(17,x0,0,0) STEPQ(18,x0,0,0) STEPQ(19,x0,0,0)
    STEPQ(20,x0,0,0) STEPQ(21,x0,0,0) STEPQ(22,x0,0,0) STEPQ(23,x0,0,0)
    LOADX(x0, 144)
    CHUNK(x1, 1, 0) LOADX(x1, 168)
    CHUNK(x2, 2, 0) LOADX(x2, 192)
    CHUNK(x3, 3, 0) LOADX(x3, 216)

    // ---- Windows 1..18: 3 iterations x 6 windows ----
    // (buffer rotation period 3, LDS parity period 2 -> combined period 6)
    for (int h = 0; h < 3; ++h) {
        const int tg = 96 * (6*h + 1);
        DRAIN(0, tg -  96)  WINDOW(x4, x5, x0, x1, tg,       1)
        DRAIN(1, tg      )  WINDOW(x2, x3, x4, x5, tg +  96, 0)
        DRAIN(0, tg +  96)  WINDOW(x0, x1, x2, x3, tg + 192, 1)
        DRAIN(1, tg + 192)  WINDOW(x4, x5, x0, x1, tg + 288, 0)
        DRAIN(0, tg + 288)  WINDOW(x2, x3, x4, x5, tg + 384, 1)
        DRAIN(1, tg + 384)  WINDOW(x0, x1, x2, x3, tg + 480, 0)
    }

    // ---- Windows 19, 20 ----
    DRAIN(0, 1728)  WINDOW(x4, x5, x0, x1, 1824, 1)
    DRAIN(1, 1824)  WINDOW(x2, x3, x4, x5, 1920, 0)

    // ---- Tail: t = 2016..2047 (32 steps) -> ot[1]; drain w20 meanwhile ----
    DRAIN(0, 1920)
    TCHUNK(x0, 0, 1, 2016)
    TCHUNK(x1, 1, 1, 2016)
    {   // drain tail: 32 cols per row
        float4 dv[8];
        #pragma unroll
        for (int rg = 0; rg < 8; ++rg)
            dv[rg] = *reinterpret_cast<const float4*>(
                &ot[1*64*STR2 + (8*rg + dr2)*STR2 + 4*dc]);
        asm volatile("" ::: "memory");
        #pragma unroll
        for (int rg = 0; rg < 8; ++rg)
            *reinterpret_cast<float4*>(
                out + (size_t)(row0 + 8*rg + dr2)*T + 2016 + 4*dc) = dv[rg];
    }

#undef STEPQ
#undef CHUNK
#undef TSTEPQ
#undef TCHUNK
#undef WINDOW
#undef DRAIN
#undef LOADG
#undef LOADX
}

extern "C" void kernel_launch(void* const* d_in, const int* in_sizes, int n_in,
                              void* d_out, int out_size, void* d_ws, size_t ws_size,
                              hipStream_t stream) {
    const float* temp  = (const float*)d_in[0];
    const float* alpha = (const float*)d_in[1];
    const float* beta  = (const float*)d_in[2];
    const float* gamma = (const float*)d_in[3];
    const float* L0    = (const float*)d_in[4];
    const float* b0    = (const float*)d_in[5];
    const float* S0    = (const float*)d_in[6];
    float* out = (float*)d_out;

    const int N = in_sizes[4];          // L0 length (8192)
    const int T = in_sizes[0] / N;      // temp is (N, T) -> 2048

    const int grid = (N + 63) / 64;     // 128 blocks x 1 wave
    hw_kernel<<<grid, 64, 0, stream>>>(
        temp, alpha, beta, gamma, L0, b0, S0, out, N, T);
}

// Round 7
// 77.591 us; speedup vs baseline: 3.0869x; 3.0869x over previous
//
#include <hip/hip_runtime.h>

// Holt-Winters, round 7: LDS-staged x via global_load_lds (double-buffered
// tiles, counted vmcnt) + LDS transpose drain for out.
// 128 blocks x 64 threads (1 wave each); block owns 64 rows (row == lane).
//
// x tile = [64 rows][96 cols] staged by 24 global_load_lds (1KB each, 16B/lane).
// Load-side lane mapping pre-swizzles cols (xcol = 4*((u&7)^(u>>3))) so the
// forced-linear LDS layout reads back conflict-free with ds_read_b128:
//   read byte = 3072*(l>>3) + 128*(l&7) + 1024*(q>>3) + (16*(q&7))^(16*(l&7))
// Compute: 8 VALU/step, 2-FMA critical chain (L, c=L+b). x read 3 groups
// (12 steps) ahead via 3 rotating float4 regs (static indices, rule #20).
// Out staged in LDS [64][100] (conflict-free), drained per window as
// 8 rows x 128B full-line stores. One s_waitcnt vmcnt(24) per window --
// drain stores stay in flight across windows, loads have a full-window
// lookahead. Hardcoded for N%64==0, T=2048 (21 windows of 96 + 32 tail).

__global__ __launch_bounds__(64, 1) void hw_kernel(
    const float* __restrict__ temp,
    const float* __restrict__ alpha,
    const float* __restrict__ beta,
    const float* __restrict__ gamma,
    const float* __restrict__ L0,
    const float* __restrict__ b0,
    const float* __restrict__ S0,
    float* __restrict__ out,
    int N, int T)
{
    __shared__ float xlds[2 * 6144];   // 2 x-tiles, 24 KB each
    __shared__ float ot[64 * 100];     // out tile, 25.6 KB

    const int lane = threadIdx.x;
    const int row0 = blockIdx.x * 64;
    const int row  = row0 + lane;
    const int ln8  = lane >> 3;
    const int l7   = lane & 7;
    const int xcol = 4 * (l7 ^ ln8);          // load-side col swizzle
    const int EX   = 16 * l7;                 // read-side xor term

    const float* lanebase = temp + (size_t)(row0 + ln8) * T + xcol;
    const char*  xrb = (const char*)xlds + ln8 * 3072 + l7 * 128;

    // Issue one x tile (cols [TB,TB+32*NK)) into LDS at float offset PARF.
#define GLL_TILE(TB, PARF, NK) { \
    _Pragma("unroll") for (int j = 0; j < 8; ++j) { \
      _Pragma("unroll") for (int k = 0; k < (NK); ++k) { \
        __builtin_amdgcn_global_load_lds( \
          (const __attribute__((address_space(1))) void*)(lanebase + (size_t)(8*j)*T + (TB) + 32*k), \
          (__attribute__((address_space(3))) void*)(&xlds[(PARF) + (j*3 + k) * 256]), \
          16, 0, 0); \
    } } }

    // Read x group Q (cols 4Q..4Q+3 of current tile) for this lane's row.
#define XRD(XV, Q, PARB) { XV = *reinterpret_cast<const float4*>( \
        xrb + (PARB) + 1024*((Q) >> 3) + ((16*((Q) & 7)) ^ EX)); }

    // ---- prologue: start DMA for tiles 0 and 1, then load state ----
    GLL_TILE(0,   0,    3)
    GLL_TILE(96,  6144, 3)

    const float a_  = alpha[0];
    const float bt  = beta[0];
    const float g_  = gamma[0];
    const float oma = 1.0f - a_;
    const float omb = 1.0f - bt;
    const float opb = 1.0f + bt;

    float buf[24];
    {
        const float* s0r = S0 + (size_t)row * 24;
        #pragma unroll
        for (int p = 0; p < 6; ++p) {
            const float4 v = *reinterpret_cast<const float4*>(s0r + 4*p);
            buf[4*p+0]=v.x; buf[4*p+1]=v.y; buf[4*p+2]=v.z; buf[4*p+3]=v.w;
        }
    }
    float L = L0[row];
    float c = L + b0[row];
    float og[4] = {0.f, 0.f, 0.f, 0.f};

    // One step at t = wbase + 4Q + E (wbase % 24 == 0 -> phase static).
#define STEP(Q, E, XE) { \
    const float x  = (XE); \
    const float s  = buf[(4*(Q)+(E)) % 24]; \
    const float t_ = x - s; \
    const float Ln = fmaf(oma, c, a_ * t_); \
    const float t1 = fmaf(omb, c, -L); \
    const float cn = fmaf(opb, Ln, t1); \
    const float sn = fmaf(g_, t_ - Ln, s); \
    buf[(4*(Q)+(E)) % 24] = sn; \
    og[(E)] = cn * sn; \
    L = Ln; c = cn; }

#define GROUP(Q, XV) { \
    STEP(Q,0,(XV).x) STEP(Q,1,(XV).y) STEP(Q,2,(XV).z) STEP(Q,3,(XV).w) \
    *reinterpret_cast<float4*>((char*)ot + lane*400 + 16*(Q)) = \
        make_float4(og[0], og[1], og[2], og[3]); }

    // groups 1..23 with 3-deep rotating prefetch
#define WINGRP_REST(PARB) \
    GROUP(1,xb)  XRD(xb,4,PARB)  GROUP(2,xc)  XRD(xc,5,PARB)  \
    GROUP(3,xa)  XRD(xa,6,PARB)  GROUP(4,xb)  XRD(xb,7,PARB)  \
    GROUP(5,xc)  XRD(xc,8,PARB)  GROUP(6,xa)  XRD(xa,9,PARB)  \
    GROUP(7,xb)  XRD(xb,10,PARB) GROUP(8,xc)  XRD(xc,11,PARB) \
    GROUP(9,xa)  XRD(xa,12,PARB) GROUP(10,xb) XRD(xb,13,PARB) \
    GROUP(11,xc) XRD(xc,14,PARB) GROUP(12,xa) XRD(xa,15,PARB) \
    GROUP(13,xb) XRD(xb,16,PARB) GROUP(14,xc) XRD(xc,17,PARB) \
    GROUP(15,xa) XRD(xa,18,PARB) GROUP(16,xb) XRD(xb,19,PARB) \
    GROUP(17,xc) XRD(xc,20,PARB) GROUP(18,xa) XRD(xa,21,PARB) \
    GROUP(19,xb) XRD(xb,22,PARB) GROUP(20,xc) XRD(xc,23,PARB) \
    GROUP(21,xa) GROUP(22,xb)    GROUP(23,xc)

    const int dr2 = lane >> 3;
    const int dc  = lane & 7;
#define DRAIN(W0) { \
    _Pragma("unroll") for (int rg = 0; rg < 8; ++rg) { \
      _Pragma("unroll") for (int j2 = 0; j2 < 3; ++j2) { \
        const float4 v = *reinterpret_cast<const float4*>( \
            (const char*)ot + (8*rg + dr2)*400 + 128*j2 + 16*dc); \
        *reinterpret_cast<float4*>( \
            out + (size_t)(row0 + 8*rg + dr2)*T + (W0) + 32*j2 + 4*dc) = v; \
    } } }

    const int NW = T / 96;            // 21 full windows
    float4 xa, xb, xc;

    // ---- window 0 (tile 0, parity 0) ----
    asm volatile("s_waitcnt vmcnt(24)" ::: "memory");  // tile 0 resident
    XRD(xa,0,0) XRD(xb,1,0) XRD(xc,2,0)
    {   // group 0: t=0 special
        og[0] = c * buf[0];
        STEP(0,1,xa.y) STEP(0,2,xa.z) STEP(0,3,xa.w)
        *reinterpret_cast<float4*>((char*)ot + lane*400) =
            make_float4(og[0], og[1], og[2], og[3]);
        XRD(xa,3,0)
    }
    WINGRP_REST(0)
    DRAIN(0)

    // ---- windows 1..NW-1 ----
    for (int m = 1; m < NW; ++m) {
        asm volatile("s_waitcnt vmcnt(24)" ::: "memory");  // tile m resident
        const int parb  = (m & 1) * 24576;       // current tile (bytes)
        const int parfN = ((m + 1) & 1) * 6144;  // next tile (floats)
        const int tbN   = 96 * (m + 1);
        if (m + 1 < NW) { GLL_TILE(tbN, parfN, 3) }   // full 96-col tile
        else            { GLL_TILE(tbN, parfN, 1) }   // 32-col tail tile
        XRD(xa,0,parb) XRD(xb,1,parb) XRD(xc,2,parb)
        GROUP(0,xa) XRD(xa,3,parb)
        WINGRP_REST(parb)
        DRAIN(96 * m)
    }

    // ---- tail: 32 steps at base 96*NW (tile NW, 8 groups) ----
    {
        asm volatile("s_waitcnt vmcnt(24)" ::: "memory");  // tail tile resident
        const int parb = (NW & 1) * 24576;
        XRD(xa,0,parb) XRD(xb,1,parb) XRD(xc,2,parb)
        GROUP(0,xa) XRD(xa,3,parb)
        GROUP(1,xb) XRD(xb,4,parb)
        GROUP(2,xc) XRD(xc,5,parb)
        GROUP(3,xa) XRD(xa,6,parb)
        GROUP(4,xb) XRD(xb,7,parb)
        GROUP(5,xc) GROUP(6,xa) GROUP(7,xb)
        const int tf = 96 * NW;
        #pragma unroll
        for (int rg = 0; rg < 8; ++rg) {
            const float4 v = *reinterpret_cast<const float4*>(
                (const char*)ot + (8*rg + dr2)*400 + 16*dc);
            *reinterpret_cast<float4*>(
                out + (size_t)(row0 + 8*rg + dr2)*T + tf + 4*dc) = v;
        }
    }

#undef STEP
#undef GROUP
#undef WINGRP_REST
#undef DRAIN
#undef XRD
#undef GLL_TILE
}

extern "C" void kernel_launch(void* const* d_in, const int* in_sizes, int n_in,
                              void* d_out, int out_size, void* d_ws, size_t ws_size,
                              hipStream_t stream) {
    const float* temp  = (const float*)d_in[0];
    const float* alpha = (const float*)d_in[1];
    const float* beta  = (const float*)d_in[2];
    const float* gamma = (const float*)d_in[3];
    const float* L0    = (const float*)d_in[4];
    const float* b0    = (const float*)d_in[5];
    const float* S0    = (const float*)d_in[6];
    float* out = (float*)d_out;

    const int N = in_sizes[4];          // 8192
    const int T = in_sizes[0] / N;      // 2048

    const int grid = (N + 63) / 64;     // 128 blocks x 1 wave
    hw_kernel<<<grid, 64, 0, stream>>>(
        temp, alpha, beta, gamma, L0, b0, S0, out, N, T);
}

// Round 8
// 68.617 us; speedup vs baseline: 3.4906x; 1.1308x over previous
//
#include <hip/hip_runtime.h>

// Holt-Winters round 8: R5's register-prefetch scan spread over ALL 256 CUs.
// 256 blocks x 64 threads (1 wave each, 1 block/CU); block owns 32 rows.
//  - compute + x-loads on lanes 0..31 (row == row0 + lane); 32 lines/instr
//  - state (L, c=L+b): 2-FMA critical chain, 7 VALU ops/step
//  - x prefetch: static 4-chunk window; chunk Q reloaded at wt+96+24Q right
//    after consumption -> 72-step (~1200 cyc) lookahead vs ~900 cyc HBM
//  - out staged in LDS [32][100] (stride 100 dwords, conflict-light),
//    drained per 96-col window by all 64 lanes as 8-rows x 32-contiguous-
//    float (128B) full-line stores -> no write amplification
//  - every register-array index compile-time constant (rule #20)
// Requires N % 32 == 0; T % 4 == 0 (schedule hardcoded for T=2048: 21
// windows of 96 + 32-step tail, but loops are runtime-bounded).

#define RPB 32
#define STR2 100

__global__ __launch_bounds__(64, 1) void hw_kernel(
    const float* __restrict__ temp,
    const float* __restrict__ alpha,
    const float* __restrict__ beta,
    const float* __restrict__ gamma,
    const float* __restrict__ L0,
    const float* __restrict__ b0,
    const float* __restrict__ S0,
    float* __restrict__ out,
    int N, int T)
{
    __shared__ float ot[RPB * STR2];         // 12.8 KB

    const int lane = threadIdx.x;            // 0..63
    const int row0 = blockIdx.x * RPB;
    const int row  = row0 + lane;            // valid only for lane < RPB
    const bool comp = (lane < RPB);

    const float a_  = alpha[0];
    const float bt  = beta[0];
    const float g_  = gamma[0];
    const float oma = 1.0f - a_;
    const float omb = 1.0f - bt;
    const float opb = 1.0f + bt;

    const float* xrow = temp + (size_t)row * T;

    float x0[24], x1[24], x2[24], x3[24], buf[24];
    float L = 0.f, c = 0.f;
    float og[4] = {0.f, 0.f, 0.f, 0.f};

#define LOADG(B, T0, J) \
    if ((T0) + 4*(J) + 4 <= T) { \
        const float4 v = *reinterpret_cast<const float4*>(xrow + (T0) + 4*(J)); \
        B[4*(J)+0]=v.x; B[4*(J)+1]=v.y; B[4*(J)+2]=v.z; B[4*(J)+3]=v.w; }
#define LOADX(B, T0) { LOADG(B,(T0),0) LOADG(B,(T0),1) LOADG(B,(T0),2) \
                       LOADG(B,(T0),3) LOADG(B,(T0),4) LOADG(B,(T0),5) }

    if (comp) {
        // Prime 4 chunks (t = 0..95) and the state.
        LOADX(x0, 0)  LOADX(x1, 24)  LOADX(x2, 48)  LOADX(x3, 72)
        const float* s0r = S0 + (size_t)row * 24;
        #pragma unroll
        for (int p = 0; p < 6; ++p) {
            const float4 v = *reinterpret_cast<const float4*>(s0r + 4*p);
            buf[4*p+0]=v.x; buf[4*p+1]=v.y; buf[4*p+2]=v.z; buf[4*p+3]=v.w;
        }
        L = L0[row];
        c = L + b0[row];
    }

    // One step at t = wbase + 24*Q + K; wbase % 24 == 0 -> phase == K.
    // 7 VALU ops; dependent chain c -> Ln -> cn (2 FMAs).
#define STEPQ(K, B, Q) { \
    const float x  = B[(K)]; \
    const float s  = buf[(K)]; \
    const float t_ = x - s; \
    const float Ln = fmaf(oma, c, a_ * t_); \
    const float t1 = fmaf(omb, c, -L); \
    const float cn = fmaf(opb, Ln, t1); \
    const float sn = fmaf(g_, t_ - Ln, s); \
    buf[(K)] = sn; \
    og[(K)&3] = cn * sn; \
    L = Ln; c = cn; \
    if (((K)&3) == 3) \
        *reinterpret_cast<float4*>(&ot[lane*STR2 + 24*(Q) + ((K)-3)]) = \
            make_float4(og[0], og[1], og[2], og[3]); }

#define CHUNK(B, Q) { \
    STEPQ(0,B,Q)  STEPQ(1,B,Q)  STEPQ(2,B,Q)  STEPQ(3,B,Q)  \
    STEPQ(4,B,Q)  STEPQ(5,B,Q)  STEPQ(6,B,Q)  STEPQ(7,B,Q)  \
    STEPQ(8,B,Q)  STEPQ(9,B,Q)  STEPQ(10,B,Q) STEPQ(11,B,Q) \
    STEPQ(12,B,Q) STEPQ(13,B,Q) STEPQ(14,B,Q) STEPQ(15,B,Q) \
    STEPQ(16,B,Q) STEPQ(17,B,Q) STEPQ(18,B,Q) STEPQ(19,B,Q) \
    STEPQ(20,B,Q) STEPQ(21,B,Q) STEPQ(22,B,Q) STEPQ(23,B,Q) }

#define TSTEPQ(K, B, Q, TF) if ((TF) + 24*(Q) + (K) < T) STEPQ(K, B, Q)
#define TCHUNK(B, Q, TF) { \
    TSTEPQ(0,B,Q,TF)  TSTEPQ(1,B,Q,TF)  TSTEPQ(2,B,Q,TF)  TSTEPQ(3,B,Q,TF)  \
    TSTEPQ(4,B,Q,TF)  TSTEPQ(5,B,Q,TF)  TSTEPQ(6,B,Q,TF)  TSTEPQ(7,B,Q,TF)  \
    TSTEPQ(8,B,Q,TF)  TSTEPQ(9,B,Q,TF)  TSTEPQ(10,B,Q,TF) TSTEPQ(11,B,Q,TF) \
    TSTEPQ(12,B,Q,TF) TSTEPQ(13,B,Q,TF) TSTEPQ(14,B,Q,TF) TSTEPQ(15,B,Q,TF) \
    TSTEPQ(16,B,Q,TF) TSTEPQ(17,B,Q,TF) TSTEPQ(18,B,Q,TF) TSTEPQ(19,B,Q,TF) \
    TSTEPQ(20,B,Q,TF) TSTEPQ(21,B,Q,TF) TSTEPQ(22,B,Q,TF) TSTEPQ(23,B,Q,TF) }

    // Drain one 96-col window: all 64 lanes; per instr 8 rows (dr2) x 8
    // float4 slots (dc) = 32 contiguous floats per row (full 64B lines).
    const int dr2 = lane >> 3;      // 0..7 row within group of 8
    const int dc  = lane & 7;       // 0..7 float4 column
#define DRAIN(W0) { \
    _Pragma("unroll") for (int rg = 0; rg < 4; ++rg) { \
      _Pragma("unroll") for (int j2 = 0; j2 < 3; ++j2) { \
        const float4 v = *reinterpret_cast<const float4*>( \
            &ot[(8*rg + dr2)*STR2 + 32*j2 + 4*dc]); \
        *reinterpret_cast<float4*>( \
            out + (size_t)(row0 + 8*rg + dr2)*T + (W0) + 32*j2 + 4*dc) = v; \
    } } }

    const int NW = T / 96;           // 21 full windows for T=2048
    const int tf = NW * 96;          // 2016
    const int Lv = T - tf;           // 32

    // ---- Window 0: t=0 special, then t = 1..95; reload chunks for w1 ----
    if (comp) {
        og[0] = c * buf[0];          // out[:,0] = (L0+b0)*S0[:,0]
        STEPQ(1,x0,0)  STEPQ(2,x0,0)  STEPQ(3,x0,0)
        STEPQ(4,x0,0)  STEPQ(5,x0,0)  STEPQ(6,x0,0)  STEPQ(7,x0,0)
        STEPQ(8,x0,0)  STEPQ(9,x0,0)  STEPQ(10,x0,0) STEPQ(11,x0,0)
        STEPQ(12,x0,0) STEPQ(13,x0,0) STEPQ(14,x0,0) STEPQ(15,x0,0)
        STEPQ(16,x0,0) STEPQ(17,x0,0) STEPQ(18,x0,0) STEPQ(19,x0,0)
        STEPQ(20,x0,0) STEPQ(21,x0,0) STEPQ(22,x0,0) STEPQ(23,x0,0)
        LOADX(x0, 96)
        CHUNK(x1, 1) LOADX(x1, 120)
        CHUNK(x2, 2) LOADX(x2, 144)
        CHUNK(x3, 3) LOADX(x3, 168)
    }
    DRAIN(0)

    // ---- Windows 1..NW-1 (static chunk->Q mapping, no rotation) ----
    for (int m = 1; m < NW; ++m) {
        const int wt = 96 * m;
        if (comp) {
            CHUNK(x0, 0) LOADX(x0, wt + 96)
            CHUNK(x1, 1) LOADX(x1, wt + 120)
            CHUNK(x2, 2) LOADX(x2, wt + 144)
            CHUNK(x3, 3) LOADX(x3, wt + 168)
        }
        DRAIN(wt)
    }

    // ---- Tail: t = tf..T-1 (32 steps for T=2048) ----
    if (Lv > 0) {
        if (comp) {
            TCHUNK(x0, 0, tf)
            TCHUNK(x1, 1, tf)
        }
        #pragma unroll
        for (int rg = 0; rg < 4; ++rg) {
            const int base = 4*dc;
            if (base + 4 <= Lv) {
                const float4 v = *reinterpret_cast<const float4*>(
                    &ot[(8*rg + dr2)*STR2 + base]);
                *reinterpret_cast<float4*>(
                    out + (size_t)(row0 + 8*rg + dr2)*T + tf + base) = v;
            }
        }
    }

#undef STEPQ
#undef CHUNK
#undef TSTEPQ
#undef TCHUNK
#undef DRAIN
#undef LOADG
#undef LOADX
}

extern "C" void kernel_launch(void* const* d_in, const int* in_sizes, int n_in,
                              void* d_out, int out_size, void* d_ws, size_t ws_size,
                              hipStream_t stream) {
    const float* temp  = (const float*)d_in[0];
    const float* alpha = (const float*)d_in[1];
    const float* beta  = (const float*)d_in[2];
    const float* gamma = (const float*)d_in[3];
    const float* L0    = (const float*)d_in[4];
    const float* b0    = (const float*)d_in[5];
    const float* S0    = (const float*)d_in[6];
    float* out = (float*)d_out;

    const int N = in_sizes[4];          // 8192
    const int T = in_sizes[0] / N;      // 2048

    const int grid = (N + RPB - 1) / RPB;   // 256 blocks -> 1 wave per CU
    hw_kernel<<<grid, 64, 0, stream>>>(
        temp, alpha, beta, gamma, L0, b0, S0, out, N, T);
}

// Round 9
// 53.165 us; speedup vs baseline: 4.5052x; 1.2906x over previous
//
#include <hip/hip_runtime.h>

// Holt-Winters round 9: R5 shape + compiler-proof software pipeline.
// 128 blocks x 64 threads (1 wave each); lane owns row row0+lane; all lanes
// compute. ALL global loads/stores are inline-asm (volatile) so hipcc cannot
// sink loads (R5's silent failure, VGPR=124) or spill them (R6/R8, VGPR=256):
//  - window = 48 cols (2 seasonal periods -> static phases, rule #20)
//  - x double-buffered in registers: A[12] / B[12] float4, issued one full
//    window ahead via asm global_load_dwordx4
//  - out staged in LDS ot[2][64][52] (stride 52 dwords: (13*lane+q)%8 uniform
//    -> conflict-free b128), drained one window behind as 12 asm
//    global_store_dwordx4 (16 rows x 64B full lines -> no write amp)
//  - consumption gated by counted `s_waitcnt vmcnt(N)` + sched_barrier(0)
//    (rule #18); stores never drained to 0 in the loop (T4)
// Hardcoded for N%64==0, T=2048 (42 windows of 48 + 32-col tail).

typedef float f32x4 __attribute__((ext_vector_type(4)));

#define ALOAD(DST, PTR, OFF) \
  asm volatile("global_load_dwordx4 %0, %1, off offset:" #OFF \
               : "=v"(DST) : "v"(PTR));

#define ASTORE(PTR, VAL) \
  asm volatile("global_store_dwordx4 %0, %1, off" :: "v"(PTR), "v"(VAL));

#define WAITVM(N) \
  { asm volatile("s_waitcnt vmcnt(" #N ") expcnt(0)" ::: "memory"); \
    __builtin_amdgcn_sched_barrier(0); }

__global__ __launch_bounds__(64, 1) void hw_kernel(
    const float* __restrict__ temp,
    const float* __restrict__ alpha,
    const float* __restrict__ beta,
    const float* __restrict__ gamma,
    const float* __restrict__ L0,
    const float* __restrict__ b0,
    const float* __restrict__ S0,
    float* __restrict__ out,
    int N, int T)
{
    __shared__ float ot[2][64 * 52];         // 26.6 KB

    const int lane = threadIdx.x;            // 0..63, owns one row
    const int row0 = blockIdx.x * 64;
    const int row  = row0 + lane;
    const float* xrow = temp + (size_t)row * T;

    f32x4 A0,A1,A2,A3,A4,A5,A6,A7,A8,A9,A10,A11;
    f32x4 B0,B1,B2,B3,B4,B5,B6,B7,B8,B9,B10,B11;

#define ISSUE12(Xp, P) { \
  ALOAD(Xp##0,(P),0)    ALOAD(Xp##1,(P),16)  ALOAD(Xp##2,(P),32)  \
  ALOAD(Xp##3,(P),48)   ALOAD(Xp##4,(P),64)  ALOAD(Xp##5,(P),80)  \
  ALOAD(Xp##6,(P),96)   ALOAD(Xp##7,(P),112) ALOAD(Xp##8,(P),128) \
  ALOAD(Xp##9,(P),144)  ALOAD(Xp##10,(P),160) ALOAD(Xp##11,(P),176) }
#define ISSUE8(Xp, P) { \
  ALOAD(Xp##0,(P),0)    ALOAD(Xp##1,(P),16)  ALOAD(Xp##2,(P),32)  \
  ALOAD(Xp##3,(P),48)   ALOAD(Xp##4,(P),64)  ALOAD(Xp##5,(P),80)  \
  ALOAD(Xp##6,(P),96)   ALOAD(Xp##7,(P),112) }

    // Prologue: issue windows 0 (A) and 1 (B) immediately.
    ISSUE12(A, xrow)
    ISSUE12(B, xrow + 48)
    const float* vaddr = xrow + 96;          // next issue base (window 2)

    // State (compiler-managed loads; any conservative drain here is one-time).
    const float a_  = alpha[0];
    const float bt  = beta[0];
    const float g_  = gamma[0];
    const float oma = 1.0f - a_;
    const float omb = 1.0f - bt;
    const float opb = 1.0f + bt;

    float buf[24];
    {
        const float* s0r = S0 + (size_t)row * 24;
        #pragma unroll
        for (int p = 0; p < 6; ++p) {
            const f32x4 v = *reinterpret_cast<const f32x4*>(s0r + 4*p);
            buf[4*p]=v.x; buf[4*p+1]=v.y; buf[4*p+2]=v.z; buf[4*p+3]=v.w;
        }
    }
    float L = L0[row];
    float c = L + b0[row];
    float og[4];

    // One step at window_base + 4Q + E; window_base % 24 == 0 -> phase static.
#define GSTEP(Q, E, XE) { \
    const float x_ = (XE); \
    const float s_ = buf[(4*(Q)+(E)) % 24]; \
    const float d_ = x_ - s_; \
    const float Ln = fmaf(oma, c, a_ * d_); \
    const float t1 = fmaf(omb, c, -L); \
    const float cn = fmaf(opb, Ln, t1); \
    const float sn = fmaf(g_, d_ - Ln, s_); \
    buf[(4*(Q)+(E)) % 24] = sn; \
    og[(E)] = cn * sn; \
    L = Ln; c = cn; }

#define GROUP(Q, XV, P) { \
    GSTEP(Q,0,(XV).x) GSTEP(Q,1,(XV).y) GSTEP(Q,2,(XV).z) GSTEP(Q,3,(XV).w) \
    *reinterpret_cast<f32x4*>(&ot[P][lane*52 + 4*(Q)]) = \
        (f32x4){og[0],og[1],og[2],og[3]}; }

#define WINCOMP_A(P) { GROUP(0,A0,P) GROUP(1,A1,P) GROUP(2,A2,P) GROUP(3,A3,P) \
    GROUP(4,A4,P) GROUP(5,A5,P) GROUP(6,A6,P) GROUP(7,A7,P) GROUP(8,A8,P) \
    GROUP(9,A9,P) GROUP(10,A10,P) GROUP(11,A11,P) }
#define WINCOMP_B(P) { GROUP(0,B0,P) GROUP(1,B1,P) GROUP(2,B2,P) GROUP(3,B3,P) \
    GROUP(4,B4,P) GROUP(5,B5,P) GROUP(6,B6,P) GROUP(7,B7,P) GROUP(8,B8,P) \
    GROUP(9,B9,P) GROUP(10,B10,P) GROUP(11,B11,P) }

    // Drain: 16 rows x 16 contiguous floats (64B full line) per instr.
    const int dr = lane >> 2;       // 0..15 row within group of 16
    const int dc = lane & 3;        // 0..3 float4 slot
    float* obase = out + (size_t)(row0 + dr) * T + 4*dc;

#define DRAIN1(P, RG, J) { \
    const f32x4 v_ = *reinterpret_cast<const f32x4*>( \
        &ot[P][(16*(RG)+dr)*52 + 16*(J) + 4*dc]); \
    ASTORE(obase + (size_t)(16*(RG))*T + 16*(J), v_); }

#define DRAIN(P) { \
    DRAIN1(P,0,0) DRAIN1(P,0,1) DRAIN1(P,0,2) \
    DRAIN1(P,1,0) DRAIN1(P,1,1) DRAIN1(P,1,2) \
    DRAIN1(P,2,0) DRAIN1(P,2,1) DRAIN1(P,2,2) \
    DRAIN1(P,3,0) DRAIN1(P,3,1) DRAIN1(P,3,2) \
    obase += 48; }

    // ---- window 0 (A, parity 0): wait W0 only (W1's 12 loads in flight) ----
    WAITVM(12)
    {   // group 0: t=0 special value
        og[0] = c * buf[0];
        GSTEP(0,1,A0.y) GSTEP(0,2,A0.z) GSTEP(0,3,A0.w)
        *reinterpret_cast<f32x4*>(&ot[0][lane*52]) =
            (f32x4){og[0],og[1],og[2],og[3]};
    }
    GROUP(1,A1,0)  GROUP(2,A2,0)  GROUP(3,A3,0)  GROUP(4,A4,0)
    GROUP(5,A5,0)  GROUP(6,A6,0)  GROUP(7,A7,0)  GROUP(8,A8,0)
    GROUP(9,A9,0)  GROUP(10,A10,0) GROUP(11,A11,0)

    // ---- windows 1..T/48-2 in pairs (odd=B, even=A) ----
    const int pairs = (T / 48 - 2) / 2;      // 20 for T=2048
    for (int h = 0; h < pairs; ++h) {
        // odd window: consume B; issue next even window into A; drain prev.
        ISSUE12(A, vaddr)
        vaddr += 48;
        DRAIN(0)
        WAITVM(24)
        WINCOMP_B(1)
        // even window: consume A; issue next odd window into B; drain prev.
        ISSUE12(B, vaddr)
        vaddr += 48;
        DRAIN(1)
        WAITVM(24)
        WINCOMP_A(0)
    }

    // ---- last full window (odd, B, parity 1); issue 32-col tail into A ----
    ISSUE8(A, vaddr)
    DRAIN(0)
    WAITVM(20)
    WINCOMP_B(1)

    // ---- drain last full window, then tail compute (32 steps, parity 0) ----
    DRAIN(1)
    WAITVM(12)
    GROUP(0,A0,0) GROUP(1,A1,0) GROUP(2,A2,0) GROUP(3,A3,0)
    GROUP(4,A4,0) GROUP(5,A5,0) GROUP(6,A6,0) GROUP(7,A7,0)

    // tail drain: 32 cols (rg 0..3 x j 0..1)
    DRAIN1(0,0,0) DRAIN1(0,0,1)
    DRAIN1(0,1,0) DRAIN1(0,1,1)
    DRAIN1(0,2,0) DRAIN1(0,2,1)
    DRAIN1(0,3,0) DRAIN1(0,3,1)

#undef GSTEP
#undef GROUP
#undef WINCOMP_A
#undef WINCOMP_B
#undef DRAIN1
#undef DRAIN
#undef ISSUE12
#undef ISSUE8
}

extern "C" void kernel_launch(void* const* d_in, const int* in_sizes, int n_in,
                              void* d_out, int out_size, void* d_ws, size_t ws_size,
                              hipStream_t stream) {
    const float* temp  = (const float*)d_in[0];
    const float* alpha = (const float*)d_in[1];
    const float* beta  = (const float*)d_in[2];
    const float* gamma = (const float*)d_in[3];
    const float* L0    = (const float*)d_in[4];
    const float* b0    = (const float*)d_in[5];
    const float* S0    = (const float*)d_in[6];
    float* out = (float*)d_out;

    const int N = in_sizes[4];          // 8192
    const int T = in_sizes[0] / N;      // 2048

    const int grid = (N + 63) / 64;     // 128 blocks x 1 wave
    hw_kernel<<<grid, 64, 0, stream>>>(
        temp, alpha, beta, gamma, L0, b0, S0, out, N, T);
}